// Round 3
// baseline (402.828 us; speedup 1.0000x reference)
//
#include <hip/hip_runtime.h>

// 3-layer LSTM, B=4096, T=336, F=12, H=50, fp32 in/out.
// MFMA: z^T = W'(gate-permuted, gate-prescaled) @ a^T via mfma_f32_16x16x32_f16.
// R = 4*unit + gate -> each lane's 4 accumulators = 4 gates of one unit ->
// lane-local c/h update; c in registers; weights in VGPRs (loaded once).
// LAYER-SPECIALIZED WAVES; copy-free planes (round-7).
// ROUND-8 CHANGES:
//  (a) READ-AFTER-BARRIER FULL DOUBLE-BUFFER: ALL B-fragments (self + input)
//      for tick t+1 are read from LDS immediately AFTER tick t's barrier into
//      a register double-buffer bR[2][4]. Tick bodies are pure-register
//      (MFMA+cell+store only, zero LDS reads). Removes the post-barrier
//      read->MFMA latency that all 16 waves paid in lockstep each tick
//      (rounds 6/7 only covered the input half, pre-barrier). Plane safety:
//      reads of plane[1-p] at end of tick t cannot race tick t+1 stores
//      (plane[p]); conflicting stores are 2 barriers away. Layer delay drops
//      to 1 (L0 step t, L1 t-1, L2 t-2) -> 338 ticks total.
//  (b) FUSED-DENOMINATOR CELL: sig(i)*tanh(g) = (eg-1)*rcp((1+ei)(1+eg)),
//      sig(o)*tanh(c) = (ec-1)*rcp((1+eo)(1+ec)). 10 -> 8 quarter-rate
//      transcendentals per cell (-16cy, +4cy full-rate): directly cuts the
//      dominant VALU-issue term (~780cy/SIMD/tick of trans).
// 1024 threads = 16 waves (4/SIMD); cells placed 9-10 per SIMD.

#define Bsz 4096
#define Tt  336
#define BT  16
#define NTH 1024

typedef _Float16 half8 __attribute__((ext_vector_type(8)));
typedef float    floatx4 __attribute__((ext_vector_type(4)));

// All planes: 64-half rows = 8 chunks (16B), XOR-chunk swizzle (&7).
// act0 row: [x 0..11 | h0 12..61 | pad 62..63]
// act1 row: [h1 0..49 | pad]      act2 row: [h2 0..49 | pad]
struct __align__(16) SMem {
  _Float16 act0[2][BT * 64];
  _Float16 act1[2][BT * 64];
  _Float16 act2[2][BT * 64];
};  // 12288 B

__device__ __forceinline__ int offA(int n, int L) {
  return n * 64 + ((((L >> 3) ^ n) & 7) << 3) + (L & 7);
}

// z gate-prescaled: gates i,f,o hold -log2(e)*z ; gate g holds 2*log2(e)*z.
// Fused: sig(i)*tanh(g) = (eg-1)/((1+ei)(1+eg));
//        sig(o)*tanh(c) = (ec-1)/((1+eo)(1+ec)), ec = e^{2c}.
// 4+1 exp2 + 3 rcp = 8 transcendentals.
__device__ __forceinline__ float lstm_cell(floatx4 z, float& c) {
  float ei = __builtin_amdgcn_exp2f(z[0]);
  float ef = __builtin_amdgcn_exp2f(z[1]);
  float eg = __builtin_amdgcn_exp2f(z[2]);
  float eo = __builtin_amdgcn_exp2f(z[3]);
  float fg  = __builtin_amdgcn_rcpf(1.f + ef);                    // sigmoid(f)
  float itg = (eg - 1.f) *
              __builtin_amdgcn_rcpf((1.f + ei) * (1.f + eg));     // sig(i)*tanh(g)
  c = fg * c + itg;
  float ec = __builtin_amdgcn_exp2f(2.885390082f * c);            // e^{2c}
  return (ec - 1.f) *
         __builtin_amdgcn_rcpf((1.f + eo) * (1.f + ec));          // sig(o)*tanh(c)
}

// A-fragment (8 halfs), gate-permuted + gate-prescaled.
// k in [0,lena)          -> Wa[row*lena + k]
// k in [offb, offb+lenb) -> Wb[row*lenb + (k-offb)]
// else 0. (Zero weights cover x positions / pads.)
__device__ __forceinline__ half8 wfrag2(const float* __restrict__ Wa, int lena,
                                        const float* __restrict__ Wb, int offb,
                                        int lenb, int R, int k0) {
  half8 r = {};
  int u = R >> 2, g = R & 3;
  float sc = (g == 2) ? 2.885390082f : -1.442695041f;
  if (u < 50) {
    int row = g * 50 + u;
#pragma unroll
    for (int j = 0; j < 8; ++j) {
      int k = k0 + j;
      float v = 0.f;
      if (Wa && k < lena)                          v = Wa[row * lena + k];
      else if (Wb && k >= offb && k < offb + lenb) v = Wb[row * lenb + (k - offb)];
      r[j] = (_Float16)(sc * v);
    }
  }
  return r;
}

#define MFMA(a, b, acc) __builtin_amdgcn_mfma_f32_16x16x32_f16((a), (b), (acc), 0, 0, 0)

// Straight-line cell block, shallow (L0: 2 MFMAs/cell from regs). NCC literal.
#define CELLS(NCC, pp, sw)                                              \
  {                                                                     \
    floatx4 z0 = bia[0], z1 = bia[1], z2 = bia[2];                      \
    z0 = MFMA(af[0][0], bR[pp][0], z0);                                 \
    z1 = MFMA(af[1][0], bR[pp][0], z1);                                 \
    if (NCC == 3) z2 = MFMA(af[2][0], bR[pp][0], z2);                   \
    z0 = MFMA(af[0][1], bR[pp][1], z0);                                 \
    z1 = MFMA(af[1][1], bR[pp][1], z1);                                 \
    if (NCC == 3) z2 = MFMA(af[2][1], bR[pp][1], z2);                   \
    float h0v = lstm_cell(z0, cst[0]);                                  \
    float h1v = lstm_cell(z1, cst[1]);                                  \
    if (uokk[0]) (sw)[wo[0]] = (_Float16)h0v;                           \
    if (uokk[1]) (sw)[wo[1]] = (_Float16)h1v;                           \
    if (NCC == 3) {                                                     \
      float h2v = lstm_cell(z2, cst[2]);                                \
      if (uokk[2]) (sw)[wo[2]] = (_Float16)h2v;                         \
    }                                                                   \
  }

// Straight-line cell block, deep (L1/L2: 4 MFMAs/cell from regs).
// Consume in read-issue order: self chunks 0,1 then input chunks 2,3.
#define CELLSD(NCC, pp, sw)                                             \
  {                                                                     \
    floatx4 z0 = bia[0], z1 = bia[1], z2 = bia[2];                      \
    z0 = MFMA(af[0][0], bR[pp][0], z0);                                 \
    z1 = MFMA(af[1][0], bR[pp][0], z1);                                 \
    if (NCC == 3) z2 = MFMA(af[2][0], bR[pp][0], z2);                   \
    z0 = MFMA(af[0][1], bR[pp][1], z0);                                 \
    z1 = MFMA(af[1][1], bR[pp][1], z1);                                 \
    if (NCC == 3) z2 = MFMA(af[2][1], bR[pp][1], z2);                   \
    z0 = MFMA(af[0][2], bR[pp][2], z0);                                 \
    z1 = MFMA(af[1][2], bR[pp][2], z1);                                 \
    if (NCC == 3) z2 = MFMA(af[2][2], bR[pp][2], z2);                   \
    z0 = MFMA(af[0][3], bR[pp][3], z0);                                 \
    z1 = MFMA(af[1][3], bR[pp][3], z1);                                 \
    if (NCC == 3) z2 = MFMA(af[2][3], bR[pp][3], z2);                   \
    float h0v = lstm_cell(z0, cst[0]);                                  \
    float h1v = lstm_cell(z1, cst[1]);                                  \
    if (uokk[0]) (sw)[wo[0]] = (_Float16)h0v;                           \
    if (uokk[1]) (sw)[wo[1]] = (_Float16)h1v;                           \
    if (NCC == 3) {                                                     \
      float h2v = lstm_cell(z2, cst[2]);                                \
      if (uokk[2]) (sw)[wo[2]] = (_Float16)h2v;                         \
    }                                                                   \
  }

__global__ __launch_bounds__(NTH, 4)
void lstm_mfma_kernel(const float* __restrict__ x,
                      const float* __restrict__ Wih0, const float* __restrict__ Whh0,
                      const float* __restrict__ bih0, const float* __restrict__ bhh0,
                      const float* __restrict__ Wih1, const float* __restrict__ Whh1,
                      const float* __restrict__ bih1, const float* __restrict__ bhh1,
                      const float* __restrict__ Wih2, const float* __restrict__ Whh2,
                      const float* __restrict__ bih2, const float* __restrict__ bhh2,
                      const float* __restrict__ Wlin, const float* __restrict__ blin,
                      float* __restrict__ out) {
  __shared__ SMem sm;
  const int tid  = threadIdx.x;
  const int blk  = blockIdx.x;
  const int lane = tid & 63;
  const int w    = tid >> 6;       // wave 0..15
  const int n    = lane & 15;      // batch col / A-row in tile
  const int q    = lane >> 4;      // quad

  // ---- zero LDS (h(-1)=0 for all layers/parities, pads=0) ----
  {
    int* zp = (int*)&sm;
    for (int i = tid; i < (int)(sizeof(SMem) / 4); i += NTH) zp[i] = 0;
  }

  // ---- wave -> (layer, cells) table; SIMD k hosts waves {k,k+4,k+8,k+12},
  //      placed so each SIMD gets 9-10 cells ----
  int Lw, nc, mm3[3] = {0, 0, 0};
  switch (w) {
    case 0:  Lw = 0; nc = 3; mm3[0] = 0;  mm3[1] = 1;  mm3[2] = 2;  break;
    case 1:  Lw = 0; nc = 2; mm3[0] = 3;  mm3[1] = 4;               break;
    case 2:  Lw = 0; nc = 3; mm3[0] = 5;  mm3[1] = 6;  mm3[2] = 7;  break;
    case 3:  Lw = 0; nc = 2; mm3[0] = 8;  mm3[1] = 9;               break;
    case 4:  Lw = 1; nc = 2; mm3[0] = 0;  mm3[1] = 1;               break;
    case 5:  Lw = 1; nc = 3; mm3[0] = 2;  mm3[1] = 3;  mm3[2] = 4;  break;
    case 6:  Lw = 1; nc = 2; mm3[0] = 5;  mm3[1] = 6;               break;
    case 7:  Lw = 1; nc = 3; mm3[0] = 7;  mm3[1] = 8;  mm3[2] = 9;  break;
    case 8:  Lw = 2; nc = 3; mm3[0] = 0;  mm3[1] = 1;  mm3[2] = 2;  break;
    case 9:  Lw = 2; nc = 2; mm3[0] = 3;  mm3[1] = 4;               break;
    case 10: Lw = 2; nc = 2; mm3[0] = 5;  mm3[1] = 6;               break;
    case 11: Lw = 2; nc = 2; mm3[0] = 7;  mm3[1] = 8;               break;
    case 12: Lw = 2; nc = 2; mm3[0] = 9;  mm3[1] = 10;              break;
    case 13: Lw = 0; nc = 3; mm3[0] = 10; mm3[1] = 11; mm3[2] = 12; break;
    case 14: Lw = 1; nc = 3; mm3[0] = 10; mm3[1] = 11; mm3[2] = 12; break;
    default: Lw = 2; nc = 2; mm3[0] = 11; mm3[1] = 12;              break;
  }
  const float* Wih = (Lw == 0) ? Wih0 : ((Lw == 1) ? Wih1 : Wih2);
  const float* Whh = (Lw == 0) ? Whh0 : ((Lw == 1) ? Whh1 : Whh2);
  const float* bih = (Lw == 0) ? bih0 : ((Lw == 1) ? bih1 : bih2);
  const float* bhh = (Lw == 0) ? bhh0 : ((Lw == 1) ? bhh1 : bhh2);

  // ---- per-cell weight fragments, biases, write offsets, c-state ----
  // af[i][0..1]: self chunks (k 0..63 of own plane rows)
  //   L0: [Wih0 | Whh0] packed.  L1/L2: Whh, k>=50 -> 0.
  // af[i][2..3]: input chunks (k 0..63 of producer plane rows)
  //   L1: k in [12,62) -> Wih1 (x positions zero-weighted). L2: k<50 -> Wih2.
  half8  af[3][4];
  floatx4 bia[3];
  float  cst[3] = {0.f, 0.f, 0.f};
  int    wo[3];
  bool   uokk[3];
#pragma unroll
  for (int i = 0; i < 3; ++i) {
    bia[i] = (floatx4){0, 0, 0, 0};
#pragma unroll
    for (int kc = 0; kc < 4; ++kc) af[i][kc] = (half8){};
    int m = mm3[i];
    int u = 4 * m + q;
    int uc = (u < 50) ? u : 49;
    uokk[i] = (i < nc) && (u < 50);
    wo[i] = (Lw == 0) ? offA(n, 12 + uc) : offA(n, uc);
    if (i < nc) {
      int R = 16 * m + n;
      if (Lw == 0) {
#pragma unroll
        for (int kc = 0; kc < 2; ++kc)
          af[i][kc] = wfrag2(Wih, 12, Whh, 12, 50, R, kc * 32 + q * 8);
      } else {
#pragma unroll
        for (int kc = 0; kc < 2; ++kc) {
          af[i][kc] = wfrag2(Whh, 50, nullptr, 0, 0, R, kc * 32 + q * 8); // self
          af[i][kc + 2] = (Lw == 1)
              ? wfrag2(nullptr, 0, Wih, 12, 50, R, kc * 32 + q * 8)       // in L1
              : wfrag2(Wih, 50, nullptr, 0, 0, R, kc * 32 + q * 8);       // in L2
        }
      }
      if (u < 50) {
#pragma unroll
        for (int g = 0; g < 4; ++g) {
          float sc = (g == 2) ? 2.885390082f : -1.442695041f;
          bia[i][g] = sc * (bih[g * 50 + u] + bhh[g * 50 + u]);
        }
      }
    }
  }

  // ---- lane-constant LDS read offsets (halfs; all planes 64-half rows) ----
  const int ro[2] = { offA(n, q * 8), offA(n, 32 + q * 8) };

  // ---- B-fragment register double buffer: [parity][chunk] ----
  // chunks 0,1 = self plane; 2,3 = input plane (L1/L2 only)
  half8 bR[2][4] = {};

  // ---- x stager: tid<192 = waves 0..2 (L0 waves), 16 rows x 12 feats ----
  const int sr = (tid < 192) ? tid / 12 : 0;
  const int sf = (tid < 192) ? tid - sr * 12 : 0;
  const int sxo = offA(sr, sf);
  const float* xp = x + ((size_t)(blk * BT + sr) * Tt) * 12 + sf;
  float xnext = 0.f;

  __syncthreads();   // zero-fill visible
  if (tid < 192) {
    sm.act0[0][sxo] = (_Float16)xp[0];   // x(0) into parity-0 buffer
    xnext = xp[12];                      // x(1)
  }
  __syncthreads();

  // ---- initial fragment load for tick 0 (plane 0) ----
  if (Lw == 0) {
    bR[0][0] = *(const half8*)&sm.act0[0][ro[0]];
    bR[0][1] = *(const half8*)&sm.act0[0][ro[1]];
  } else if (Lw == 1) {
    bR[0][0] = *(const half8*)&sm.act1[0][ro[0]];
    bR[0][1] = *(const half8*)&sm.act1[0][ro[1]];
    bR[0][2] = *(const half8*)&sm.act0[0][ro[0]];
    bR[0][3] = *(const half8*)&sm.act0[0][ro[1]];
  } else {
    bR[0][0] = *(const half8*)&sm.act2[0][ro[0]];
    bR[0][1] = *(const half8*)&sm.act2[0][ro[1]];
    bR[0][2] = *(const half8*)&sm.act1[0][ro[0]];
    bR[0][3] = *(const half8*)&sm.act1[0][ro[1]];
  }

  // Tick TAU (parity p = TAU&1): compute from regs bR[p], store h to
  // plane[1-p], barrier, then read bR[1-p] from plane[1-p] for TAU+1.
  // Layer delay 1: L0 step TAU (TAU<=335), L1 step TAU-1 (1<=TAU<=336),
  // L2 step TAU-2 (2<=TAU<=337). Read windows (for TAU+1):
  // L0: TAU<=334; L1: TAU<=335; L2: 1<=TAU<=336. CHK=1 -> literal folds.
#define TICK(p, TAU, CHK)                                                  \
  {                                                                        \
    if (Lw == 0) {                                                         \
      if (!(CHK) || (TAU) <= 335) {                                        \
        _Float16* sw = &sm.act0[1 - (p)][0];                               \
        if (nc == 3) CELLS(3, p, sw) else CELLS(2, p, sw)                  \
      }                                                                    \
    } else if (Lw == 1) {                                                  \
      if (!(CHK) || ((TAU) >= 1 && (TAU) <= 336)) {                        \
        _Float16* sw = &sm.act1[1 - (p)][0];                               \
        if (nc == 3) CELLSD(3, p, sw) else CELLSD(2, p, sw)                \
      }                                                                    \
    } else {                                                               \
      if (!(CHK) || ((TAU) >= 2 && (TAU) <= 337)) {                        \
        _Float16* sw = &sm.act2[1 - (p)][0];                               \
        if (nc == 3) CELLSD(3, p, sw) else CELLSD(2, p, sw)                \
      }                                                                    \
    }                                                                      \
    if (tid < 192) {                                                       \
      if ((TAU) + 1 < Tt) sm.act0[1 - (p)][sxo] = (_Float16)xnext;         \
      xnext = ((TAU) + 2 < Tt) ? xp[((TAU) + 2) * 12] : 0.f;               \
    }                                                                      \
    __syncthreads();                                                       \
    if (Lw == 0) {                                                         \
      if (!(CHK) || (TAU) <= 334) {                                        \
        bR[1 - (p)][0] = *(const half8*)&sm.act0[1 - (p)][ro[0]];          \
        bR[1 - (p)][1] = *(const half8*)&sm.act0[1 - (p)][ro[1]];          \
      }                                                                    \
    } else if (Lw == 1) {                                                  \
      if (!(CHK) || (TAU) <= 335) {                                        \
        bR[1 - (p)][0] = *(const half8*)&sm.act1[1 - (p)][ro[0]];          \
        bR[1 - (p)][1] = *(const half8*)&sm.act1[1 - (p)][ro[1]];          \
        bR[1 - (p)][2] = *(const half8*)&sm.act0[1 - (p)][ro[0]];          \
        bR[1 - (p)][3] = *(const half8*)&sm.act0[1 - (p)][ro[1]];          \
      }                                                                    \
    } else {                                                               \
      if (!(CHK) || ((TAU) >= 1 && (TAU) <= 336)) {                        \
        bR[1 - (p)][0] = *(const half8*)&sm.act2[1 - (p)][ro[0]];          \
        bR[1 - (p)][1] = *(const half8*)&sm.act2[1 - (p)][ro[1]];          \
        bR[1 - (p)][2] = *(const half8*)&sm.act1[1 - (p)][ro[0]];          \
        bR[1 - (p)][3] = *(const half8*)&sm.act1[1 - (p)][ro[1]];          \
      }                                                                    \
    }                                                                      \
  }

  // fill (literal TAU -> activity folds at compile time)
  TICK(0, 0, 1)
  TICK(1, 1, 1)
  // steady: ticks 2..335 (334 ticks, unroll-2 for literal parity)
#pragma unroll 1
  for (int t = 2; t < Tt; t += 2) {
    TICK(0, t, 0)
    TICK(1, t + 1, 0)
  }
  // drain
  TICK(0, 336, 1)
  TICK(1, 337, 1)
#undef TICK

  // ---- epilogue: out[r] = b_lin + h2(335) . W_lin ----
  // L2 step 335 ran at tick 337 (p=1) -> wrote act2[0] (halfs 0..49)
  if (tid < BT) {
    float s = blin[0];
    for (int uu = 0; uu < 50; ++uu)
      s += Wlin[uu] * (float)sm.act2[0][offA(tid, uu)];
    out[blk * BT + tid] = s;
  }
}

extern "C" void kernel_launch(void* const* d_in, const int* in_sizes, int n_in,
                              void* d_out, int out_size, void* d_ws, size_t ws_size,
                              hipStream_t stream) {
  const float* x    = (const float*)d_in[0];
  const float* Wih0 = (const float*)d_in[1];
  const float* Whh0 = (const float*)d_in[2];
  const float* bih0 = (const float*)d_in[3];
  const float* bhh0 = (const float*)d_in[4];
  const float* Wih1 = (const float*)d_in[5];
  const float* Whh1 = (const float*)d_in[6];
  const float* bih1 = (const float*)d_in[7];
  const float* bhh1 = (const float*)d_in[8];
  const float* Wih2 = (const float*)d_in[9];
  const float* Whh2 = (const float*)d_in[10];
  const float* bih2 = (const float*)d_in[11];
  const float* bhh2 = (const float*)d_in[12];
  const float* Wlin = (const float*)d_in[13];
  const float* blin = (const float*)d_in[14];
  float* outp = (float*)d_out;

  dim3 grid(Bsz / BT);   // 256 blocks, 1 per CU
  dim3 block(NTH);       // 16 waves -> 4 per SIMD
  lstm_mfma_kernel<<<grid, block, 0, stream>>>(
      x, Wih0, Whh0, bih0, bhh0, Wih1, Whh1, bih1, bhh1,
      Wih2, Whh2, bih2, bhh2, Wlin, blin, outp);
}